// Round 1
// baseline (146.767 us; speedup 1.0000x reference)
//
#include <hip/hip_runtime.h>

// SSIM, N=32 images 512x512 fp32, 11x11 Gaussian (separable via rank-1
// window), zero pad, scalar mean output.
//
// R10: occupancy attack on R9. R9 evidence: dur 43us but VALU busy ~17us,
// LDS pipe ~13.5us, HBM ~7us, Occupancy 16% -> ~26us is barrier/latency
// dead time at only 2 blocks/CU (grid 512 on 256 CUs; 46.5KB LDS blocks a
// 3rd block anyway). Fix: 4 co-resident blocks/CU so barriers in one block
// overlap compute in the other three.
//  - RROWS 32 -> 16: grid (32,32) = 1024 blocks = exactly 4/CU.
//  - chunk CH 11 -> 9 rows: LDS 9x524x8 = 37.7KB; 4 x 37.7 = 151KB <= 160KB.
//    26 streamed rows = 3 chunks (27 slots, tail slot compile-time dead).
//  - CH != 11 breaks "chunk == ring modulus": chunk loop now FULLY UNROLLED
//    (3 chunks) so every ring index i%11 stays a compile-time constant
//    (runtime-indexed ext_vector arrays spill to scratch).
//  - Cost: halo amplification 42/32 -> 26/16 (~1.24x horizontal work); the
//    extra reads come from LLC, not HBM.
// R8/R9 kept: packed fp32 (v_pk_*) on (s,d)=(x+y,x-y), M=2 cols/thread,
// TW=256 spans the row, per-row edge zeros, 2 barriers/chunk with all
// next-chunk loads issued right after the first barrier, same epilogue.
// No min-waves launch_bounds (R3: VGPR cap => 244MB scratch spill).

typedef float v2f __attribute__((ext_vector_type(2)));
typedef float v4f __attribute__((ext_vector_type(4)));

#define IMG_H 512
#define IMG_W 512
#define NIMG  32
#define NT    256
#define RROWS 16
#define ITERS (RROWS + 10)   // 26 input rows streamed
#define CH    9              // chunk rows (LDS buffer rows)
#define NCHNK 3              // ceil(26/9)
// LDS row: idx 0 pad | 1..5 zeroL | 6..517 data (col c -> idx 6+c) |
//          518..522 zeroR | 523 pad
#define LDSW  524

#define C1F  1.0e-4f
#define C2F  9.0e-4f
#define EPSF 1.0e-8f

static __device__ __forceinline__ v2f pkfma(float s, v2f a, v2f b) {
    v2f sv = {s, s};
    return __builtin_elementwise_fma(sv, a, b);   // -> v_pk_fma_f32
}

__global__ __launch_bounds__(NT) void ssim_kernel(
    const float* __restrict__ xg, const float* __restrict__ yg,
    const float* __restrict__ wg, float* __restrict__ out)
{
    const int t    = threadIdx.x;       // 0..255
    const int lane = t & 63;
    const int chnk = blockIdx.x;        // 0..31
    const int img  = blockIdx.y;        // 0..31
    const int r0   = chnk * RROWS;
    const int c0   = 2 * t;             // own columns c0, c0+1

    const float* xb = xg + (size_t)img * (IMG_H * IMG_W);
    const float* yb = yg + (size_t)img * (IMG_H * IMG_W);

    __shared__ alignas(16) v2f ssd[CH][LDSW];   // 9-row (s,d) buffer, 37.7KB
    __shared__ float wredS[4];

    // 1D taps = row sums of normalized 2D window -> SGPRs via readfirstlane.
    float rs = 0.f;
    if (lane < 11) {
        #pragma unroll
        for (int j = 0; j < 11; ++j) rs += wg[lane * 11 + j];
    }
    float g[11];
    #pragma unroll
    for (int k = 0; k < 11; ++k) {
        int gi = __shfl(__float_as_int(rs), k, 64);
        g[k] = __int_as_float(__builtin_amdgcn_readfirstlane(gi));
    }

    const v2f z2 = {0.f, 0.f};

    // per-row static edge zeros (image boundary), written once; data writes
    // never touch idx 1..5 / 518..522. Visible after first barrier.
    if (t < 45)               { ssd[t / 5][1 + t % 5] = z2; }           // 9*5
    if (t >= 128 && t < 173)  { const int u = t - 128; ssd[u / 5][518 + u % 5] = z2; }

    // pending next-chunk loads (registers): 9 rows x (x,y) float2 = 36 VGPR
    v2f px[CH], py[CH];
    #pragma unroll
    for (int m = 0; m < CH; ++m) {
        const int r = r0 - 5 + m;
        if ((unsigned)r < IMG_H) {
            px[m] = *(const v2f*)(xb + (size_t)r * IMG_W + c0);
            py[m] = *(const v2f*)(yb + (size_t)r * IMG_W + c0);
        } else { px[m] = z2; py[m] = z2; }
    }

    // vertical register rings, modulus 11: (s,d),(s2,d2) x 2 cols x 11 rows
    v2f rSD[11][2], rQ[11][2];

    float acc = 0.f;

    #pragma unroll    // FULL unroll: ring indices i%11 must stay static
    for (int c = 0; c < NCHNK; ++c) {
        // ---- write phase: convert pending rows to (s,d), stage to LDS ----
        #pragma unroll
        for (int m = 0; m < CH; ++m) {
            if (CH * c + m < ITERS) {           // compile-time tail guard
                const v2f sv = px[m] + py[m];   // v_pk_add_f32
                const v2f dv = px[m] - py[m];
                v4f st = {sv.x, dv.x, sv.y, dv.y};
                *(v4f*)&ssd[m][6 + c0] = st;
            }
        }
        __syncthreads();

        // ---- issue ALL next-chunk loads (consumed after next barrier) ----
        if (c < NCHNK - 1) {
            #pragma unroll
            for (int m = 0; m < CH; ++m) {
                const int in_ = CH * (c + 1) + m;
                if (in_ < ITERS) {              // compile-time tail guard
                    const int r = r0 - 5 + in_;
                    if ((unsigned)r < IMG_H) {
                        px[m] = *(const v2f*)(xb + (size_t)r * IMG_W + c0);
                        py[m] = *(const v2f*)(yb + (size_t)r * IMG_W + c0);
                    } else { px[m] = z2; py[m] = z2; }
                }
            }
        }

        // ---- compute phase: up to 9 row-iterations from LDS ----
        #pragma unroll
        for (int s = 0; s < CH; ++s) {
            const int i = CH * c + s;           // global streamed-row index
            if (i >= ITERS) continue;           // compile-time (c=2, s=8)
            // horizontal conv, both cols; window element j (0..13) at LDS
            // idx c0+j (col c0-6+j); 7 b128 reads, squares once per elem.
            v2f hA = z2, hB = z2, qA = z2, qB = z2;
            #pragma unroll
            for (int m = 0; m < 7; ++m) {
                const v4f w4 = *(const v4f*)&ssd[s][c0 + 2 * m];
                const v2f e0 = {w4.x, w4.y};   // j = 2m
                const v2f e1 = {w4.z, w4.w};   // j = 2m+1
                {
                    const int j = 2 * m;
                    if (j >= 1) {
                        const v2f f0 = e0 * e0;          // v_pk_mul_f32
                        if (j <= 11) {
                            hA = pkfma(g[j - 1], e0, hA);
                            qA = pkfma(g[j - 1], f0, qA);
                        }
                        if (j >= 2) {
                            hB = pkfma(g[j - 2], e0, hB);
                            qB = pkfma(g[j - 2], f0, qB);
                        }
                    }
                }
                {
                    const int j = 2 * m + 1;
                    if (j <= 12) {
                        const v2f f1 = e1 * e1;
                        if (j <= 11) {
                            hA = pkfma(g[j - 1], e1, hA);
                            qA = pkfma(g[j - 1], f1, qA);
                        }
                        if (j >= 2) {
                            hB = pkfma(g[j - 2], e1, hB);
                            qB = pkfma(g[j - 2], f1, qB);
                        }
                    }
                }
            }
            const int sl0 = i % 11;             // static after unroll
            rSD[sl0][0] = hA; rSD[sl0][1] = hB;
            rQ[sl0][0]  = qA; rQ[sl0][1]  = qB;

            if (i >= 10) {                      // output row r0 + i - 10
                #pragma unroll
                for (int cc = 0; cc < 2; ++cc) {
                    v2f mSD = z2, mQ = z2;
                    #pragma unroll
                    for (int j = 0; j < 11; ++j) {
                        const int sl = (i + 1 + j) % 11;   // static
                        mSD = pkfma(g[j], rSD[sl][cc], mSD);
                        mQ  = pkfma(g[j], rQ[sl][cc],  mQ);
                    }
                    const v2f t2 = mSD * mSD;      // (mS^2, mD^2)
                    const float a    = 0.5f  * (t2.x + t2.y); // mx2+my2
                    const float muxy = 0.25f * (t2.x - t2.y); // mx*my
                    const float ep   = 0.5f  * (mQ.x + mQ.y); // Ex2+Ey2
                    const float eq   = 0.25f * (mQ.x - mQ.y); // Exy
                    const float sxy  = eq - muxy;
                    const float ssum = ep - a;
                    const float num  = fmaf(2.f, muxy, C1F) * fmaf(2.f, sxy, C2F);
                    const float den  = (a + C1F) * (ssum + C2F);
                    float v = num * __builtin_amdgcn_rcpf(den + EPSF);
                    acc += fminf(fmaxf(v, 0.f), 1.f);
                }
            }
        }
        if (c < NCHNK - 1) __syncthreads();   // protect buffer from next writes
    }

    // block reduction: wave shuffle, 4 slots in LDS, one atomic per block
    #pragma unroll
    for (int off = 32; off > 0; off >>= 1)
        acc += __shfl_down(acc, off, 64);
    if (lane == 0) wredS[t >> 6] = acc;
    __syncthreads();
    if (t == 0) {
        const float tot = (wredS[0] + wredS[1]) + (wredS[2] + wredS[3]);
        atomicAdd(out, tot * (1.0f / (float)((size_t)NIMG * IMG_H * IMG_W)));
    }
}

extern "C" void kernel_launch(void* const* d_in, const int* in_sizes, int n_in,
                              void* d_out, int out_size, void* d_ws, size_t ws_size,
                              hipStream_t stream) {
    const float* x = (const float*)d_in[0];
    const float* y = (const float*)d_in[1];
    const float* w = (const float*)d_in[2];
    float* out = (float*)d_out;

    // d_out is re-poisoned to 0xAA before every timed launch; zero it first.
    hipMemsetAsync(out, 0, sizeof(float), stream);

    dim3 grid(IMG_H / RROWS, NIMG);    // (32, 32) = 1024 blocks x 4 waves
    ssim_kernel<<<grid, dim3(NT), 0, stream>>>(x, y, w, out);
}

// Round 2
// 117.756 us; speedup vs baseline: 1.2464x; 1.2464x over previous
//
#include <hip/hip_runtime.h>

// SSIM, N=32 images 512x512 fp32, 11x11 Gaussian (separable via rank-1
// window), zero pad, scalar mean output.
//
// R11: R9 body EXACTLY (proven 43.7us, 84 VGPR), only the grid changes.
// R10 post-mortem: CH=9 + full chunk unroll -> 176 VGPR -> still 2
// blocks/CU, occupancy theory never tested (81us, regression). The
// invariants that keep VGPR at 84 are (a) chunk loop `#pragma unroll 1`,
// (b) CH == ring modulus 11 so all ring indices are static WITHOUT
// unrolling the chunk loop. Do not break them.
// R11 occupancy fix with zero body changes: R9's 46.6KB LDS already
// permits 3 blocks/CU (3x46.6=140KB <= 160KB) and 84 VGPR permits 6
// waves/SIMD; R9's grid (16,32)=512 was just too small (2/CU). Set
// RROWS 32 -> 22: grid (24,32) = 768 blocks = exactly 3/CU. Barriers in
// one block now overlap compute in the other two.
//  - RROWS=22 doesn't divide 512: last chunk per image outputs 6 rows;
//    one wave-uniform guard (orow < 512) on the epilogue; input loads
//    were already range-guarded.
//  - Cost: halo 32/22 vs 42/32 -> 1.14x total row-iterations (LLC-fed).
// R8/R9 kept: packed fp32 (v_pk_*) on (s,d)=(x+y,x-y), M=2 cols/thread,
// TW=256 spans the row, per-row edge zeros, 2 barriers/chunk, all
// next-chunk loads issued right after the first barrier, same epilogue.
// No min-waves launch_bounds (R3: VGPR cap => 244MB scratch spill).

typedef float v2f __attribute__((ext_vector_type(2)));
typedef float v4f __attribute__((ext_vector_type(4)));

#define IMG_H 512
#define IMG_W 512
#define NIMG  32
#define NT    256
#define RROWS 22
#define ITERS (RROWS + 10)   // 32 input rows streamed
#define CH    11             // chunk rows == ring modulus (invariant!)
#define NCHNK 3              // ceil(32/11)
// LDS row: idx 0 pad | 1..5 zeroL | 6..517 data (col c -> idx 6+c) |
//          518..522 zeroR | 523 pad
#define LDSW  524

#define C1F  1.0e-4f
#define C2F  9.0e-4f
#define EPSF 1.0e-8f

static __device__ __forceinline__ v2f pkfma(float s, v2f a, v2f b) {
    v2f sv = {s, s};
    return __builtin_elementwise_fma(sv, a, b);   // -> v_pk_fma_f32
}

__global__ __launch_bounds__(NT) void ssim_kernel(
    const float* __restrict__ xg, const float* __restrict__ yg,
    const float* __restrict__ wg, float* __restrict__ out)
{
    const int t    = threadIdx.x;       // 0..255
    const int lane = t & 63;
    const int chnk = blockIdx.x;        // 0..23
    const int img  = blockIdx.y;        // 0..31
    const int r0   = chnk * RROWS;
    const int c0   = 2 * t;             // own columns c0, c0+1

    const float* xb = xg + (size_t)img * (IMG_H * IMG_W);
    const float* yb = yg + (size_t)img * (IMG_H * IMG_W);

    __shared__ alignas(16) v2f ssd[CH][LDSW];   // 11-row (s,d) buffer, 46KB
    __shared__ float wredS[4];

    // 1D taps = row sums of normalized 2D window -> SGPRs via readfirstlane.
    float rs = 0.f;
    if (lane < 11) {
        #pragma unroll
        for (int j = 0; j < 11; ++j) rs += wg[lane * 11 + j];
    }
    float g[11];
    #pragma unroll
    for (int k = 0; k < 11; ++k) {
        int gi = __shfl(__float_as_int(rs), k, 64);
        g[k] = __int_as_float(__builtin_amdgcn_readfirstlane(gi));
    }

    const v2f z2 = {0.f, 0.f};

    // per-row static edge zeros (image boundary), written once; data writes
    // never touch idx 1..5 / 518..522. Visible after first barrier.
    if (t < 55)               { ssd[t / 5][1 + t % 5] = z2; }
    if (t >= 128 && t < 183)  { const int u = t - 128; ssd[u / 5][518 + u % 5] = z2; }

    // pending next-chunk loads (registers): 11 rows x (x,y) float2 = 44 VGPR
    v2f px[CH], py[CH];
    #pragma unroll
    for (int m = 0; m < CH; ++m) {
        const int r = r0 - 5 + m;
        if ((unsigned)r < IMG_H) {
            px[m] = *(const v2f*)(xb + (size_t)r * IMG_W + c0);
            py[m] = *(const v2f*)(yb + (size_t)r * IMG_W + c0);
        } else { px[m] = z2; py[m] = z2; }
    }

    // vertical register rings: (s,d),(s2,d2) x 2 cols x 11 rows = 88 floats
    v2f rSD[CH][2], rQ[CH][2];

    float acc = 0.f;

    #pragma unroll 1
    for (int c = 0; c < NCHNK; ++c) {
        // ---- write phase: convert pending rows to (s,d), stage to LDS ----
        #pragma unroll
        for (int m = 0; m < CH; ++m) {
            const v2f sv = px[m] + py[m];       // v_pk_add_f32
            const v2f dv = px[m] - py[m];
            v4f st = {sv.x, dv.x, sv.y, dv.y};
            *(v4f*)&ssd[m][6 + c0] = st;
        }
        __syncthreads();

        // ---- issue ALL next-chunk loads (consumed after next barrier) ----
        if (c < NCHNK - 1) {
            #pragma unroll
            for (int m = 0; m < CH; ++m) {
                const int r = r0 + 6 + CH * c + m;
                if ((unsigned)r < IMG_H) {
                    px[m] = *(const v2f*)(xb + (size_t)r * IMG_W + c0);
                    py[m] = *(const v2f*)(yb + (size_t)r * IMG_W + c0);
                } else { px[m] = z2; py[m] = z2; }
            }
        }

        // ---- compute phase: 11 row-iterations from LDS ----
        #pragma unroll
        for (int s = 0; s < CH; ++s) {
            const int i = CH * c + s;
            // horizontal conv, both cols; window element j (0..13) at LDS
            // idx c0+j (col c0-6+j); 7 b128 reads, squares once per elem.
            v2f hA = z2, hB = z2, qA = z2, qB = z2;
            #pragma unroll
            for (int m = 0; m < 7; ++m) {
                const v4f w4 = *(const v4f*)&ssd[s][c0 + 2 * m];
                const v2f e0 = {w4.x, w4.y};   // j = 2m
                const v2f e1 = {w4.z, w4.w};   // j = 2m+1
                {
                    const int j = 2 * m;
                    if (j >= 1) {
                        const v2f f0 = e0 * e0;          // v_pk_mul_f32
                        if (j <= 11) {
                            hA = pkfma(g[j - 1], e0, hA);
                            qA = pkfma(g[j - 1], f0, qA);
                        }
                        if (j >= 2) {
                            hB = pkfma(g[j - 2], e0, hB);
                            qB = pkfma(g[j - 2], f0, qB);
                        }
                    }
                }
                {
                    const int j = 2 * m + 1;
                    if (j <= 12) {
                        const v2f f1 = e1 * e1;
                        if (j <= 11) {
                            hA = pkfma(g[j - 1], e1, hA);
                            qA = pkfma(g[j - 1], f1, qA);
                        }
                        if (j >= 2) {
                            hB = pkfma(g[j - 2], e1, hB);
                            qB = pkfma(g[j - 2], f1, qB);
                        }
                    }
                }
            }
            rSD[s][0] = hA; rSD[s][1] = hB;
            rQ[s][0]  = qA; rQ[s][1]  = qB;

            if (i >= 10 && i < ITERS) {         // output row r0 + i - 10
                const int orow = r0 + i - 10;
                if (orow < IMG_H) {             // wave-uniform tail guard
                    #pragma unroll
                    for (int cc = 0; cc < 2; ++cc) {
                        v2f mSD = z2, mQ = z2;
                        #pragma unroll
                        for (int j = 0; j < 11; ++j) {
                            const int sl = (s + 1 + j) % 11;   // static
                            mSD = pkfma(g[j], rSD[sl][cc], mSD);
                            mQ  = pkfma(g[j], rQ[sl][cc],  mQ);
                        }
                        const v2f t2 = mSD * mSD;      // (mS^2, mD^2)
                        const float a    = 0.5f  * (t2.x + t2.y); // mx2+my2
                        const float muxy = 0.25f * (t2.x - t2.y); // mx*my
                        const float ep   = 0.5f  * (mQ.x + mQ.y); // Ex2+Ey2
                        const float eq   = 0.25f * (mQ.x - mQ.y); // Exy
                        const float sxy  = eq - muxy;
                        const float ssum = ep - a;
                        const float num  = fmaf(2.f, muxy, C1F) * fmaf(2.f, sxy, C2F);
                        const float den  = (a + C1F) * (ssum + C2F);
                        float v = num * __builtin_amdgcn_rcpf(den + EPSF);
                        acc += fminf(fmaxf(v, 0.f), 1.f);
                    }
                }
            }
        }
        __syncthreads();   // protect buffer from next chunk's writes
    }

    // block reduction: wave shuffle, 4 slots in LDS, one atomic per block
    #pragma unroll
    for (int off = 32; off > 0; off >>= 1)
        acc += __shfl_down(acc, off, 64);
    if (lane == 0) wredS[t >> 6] = acc;
    __syncthreads();
    if (t == 0) {
        const float tot = (wredS[0] + wredS[1]) + (wredS[2] + wredS[3]);
        atomicAdd(out, tot * (1.0f / (float)((size_t)NIMG * IMG_H * IMG_W)));
    }
}

extern "C" void kernel_launch(void* const* d_in, const int* in_sizes, int n_in,
                              void* d_out, int out_size, void* d_ws, size_t ws_size,
                              hipStream_t stream) {
    const float* x = (const float*)d_in[0];
    const float* y = (const float*)d_in[1];
    const float* w = (const float*)d_in[2];
    float* out = (float*)d_out;

    // d_out is re-poisoned to 0xAA before every timed launch; zero it first.
    hipMemsetAsync(out, 0, sizeof(float), stream);

    dim3 grid((IMG_H + RROWS - 1) / RROWS, NIMG);  // (24, 32) = 768 = 3/CU
    ssim_kernel<<<grid, dim3(NT), 0, stream>>>(x, y, w, out);
}

// Round 3
// 117.190 us; speedup vs baseline: 1.2524x; 1.0048x over previous
//
#include <hip/hip_runtime.h>

// SSIM, N=32 images 512x512 fp32, 11x11 Gaussian (separable via rank-1
// window), zero pad, scalar mean output.
//
// R12: BARRIER-FREE restructure. R11 post-mortem: 3 blocks/CU co-resident
// (occupancy 23%) gave only the work-scaling (~15%), none of the predicted
// barrier absorption -- identical blocks launched together run PHASE-LOCKED,
// all 12 waves hit the __syncthreads + vmcnt/lgkm drains simultaneously, so
// there is never an out-of-phase block to overlap with. The block-wide
// barrier design itself is the dead time.
// Fix: wave-private staging. Each wave owns a 128-col segment and stages its
// own 140-col (s,d) halo row into a private 1.1KB LDS segment. Producer ==
// consumer wave; DS ops from one wave complete in order, so write->read
// needs only the compiler's lgkmcnt. ZERO __syncthreads in the main loop
// (one only before the final block reduction). Waves run free; stalls are
// per-wave latency, hidden by TLP.
//  - RROWS=23 -> ITERS=33 = 3x11: outer `#pragma unroll 1` over base, inner
//    unroll-11 -> all ring indices static WITHOUT unrolling the outer loop
//    (R10 lesson: per-step live set is 1 pending row, keeps VGPR low).
//  - halo cols (6L+6R) loaded redundantly by lanes 0-2 / 61-63; image-edge
//    zeros fall out of the (unsigned) range guards -- no prologue writes.
//  - iso-work vs R11 (0.99x): gain attributable purely to barrier removal.
// R8-R11 kept: packed fp32 (v_pk_*) on (s,d)=(x+y,x-y), M=2 cols/thread,
// 7x ds_read_b128 horizontal window, 11-slot register rings, same epilogue.

typedef float v2f __attribute__((ext_vector_type(2)));
typedef float v4f __attribute__((ext_vector_type(4)));

#define IMG_H 512
#define IMG_W 512
#define NIMG  32
#define NT    256
#define RROWS 23
#define ITERS (RROWS + 10)   // 33 = 3 x 11, exact
// per-wave LDS segment: idx 0..139 hold (s,d) of cols C0-6 .. C0+133
// (idx i <-> col C0-6+i). 140 used, pad stride to 144 v2f (1152 B).
#define SEGW  144

#define C1F  1.0e-4f
#define C2F  9.0e-4f
#define EPSF 1.0e-8f

static __device__ __forceinline__ v2f pkfma(float s, v2f a, v2f b) {
    v2f sv = {s, s};
    return __builtin_elementwise_fma(sv, a, b);   // -> v_pk_fma_f32
}

__global__ __launch_bounds__(NT) void ssim_kernel(
    const float* __restrict__ xg, const float* __restrict__ yg,
    const float* __restrict__ wg, float* __restrict__ out)
{
    const int t    = threadIdx.x;       // 0..255
    const int lane = t & 63;
    const int wv   = t >> 6;            // wave id 0..3 -> col segment
    const int chnk = blockIdx.x;        // 0..22
    const int img  = blockIdx.y;        // 0..31
    const int r0   = chnk * RROWS;
    const int C0   = 128 * wv;          // segment col base
    const int cown = C0 + 2 * lane;     // owned cols cown, cown+1
    const int c0l  = 2 * lane;          // local LDS read base (idx units)

    const float* xb = xg + (size_t)img * (IMG_H * IMG_W);
    const float* yb = yg + (size_t)img * (IMG_H * IMG_W);

    __shared__ alignas(16) v2f seg[4][SEGW];   // 4 wave-private rows, 4.6KB
    __shared__ float wredS[4];

    // 1D taps = row sums of normalized 2D window -> SGPRs via readfirstlane.
    float rs = 0.f;
    if (lane < 11) {
        #pragma unroll
        for (int j = 0; j < 11; ++j) rs += wg[lane * 11 + j];
    }
    float g[11];
    #pragma unroll
    for (int k = 0; k < 11; ++k) {
        int gi = __shfl(__float_as_int(rs), k, 64);
        g[k] = __int_as_float(__builtin_amdgcn_readfirstlane(gi));
    }

    const v2f z2 = {0.f, 0.f};

    // halo duty: lanes 0..2 left (cols C0-6+2*lane), lanes 61..63 right
    // (cols C0+128+2*(lane-61)). Out-of-image -> z2 via range guard.
    const bool isH = (lane < 3) || (lane >= 61);
    const int  hcol = (lane < 3) ? (C0 - 6 + 2 * lane)
                                 : (C0 + 128 + 2 * (lane - 61));
    const int  hidx = (lane < 3) ? (2 * lane) : (134 + 2 * (lane - 61));

    // pending-row registers (1 row deep)
    v2f px, py, hx, hy;
    {   // prologue: load row r0-5
        const int r = r0 - 5;
        px = z2; py = z2; hx = z2; hy = z2;
        if ((unsigned)r < IMG_H) {
            const float* xr = xb + (size_t)r * IMG_W;
            const float* yr = yb + (size_t)r * IMG_W;
            px = *(const v2f*)(xr + cown);
            py = *(const v2f*)(yr + cown);
            if (isH && (unsigned)hcol < IMG_W) {
                hx = *(const v2f*)(xr + hcol);
                hy = *(const v2f*)(yr + hcol);
            }
        }
    }

    // vertical register rings: (s,d),(s2,d2) x 2 cols x 11 rows
    v2f rSD[11][2], rQ[11][2];

    float acc = 0.f;

    #pragma unroll 1
    for (int base = 0; base < ITERS; base += 11) {
        #pragma unroll
        for (int s = 0; s < 11; ++s) {
            const int i = base + s;     // streamed-row index, i%11 == s

            // ---- stage pending row into wave-private LDS ----
            {
                const v2f sv = px + py;          // v_pk_add_f32
                const v2f dv = px - py;
                v4f st = {sv.x, dv.x, sv.y, dv.y};
                *(v4f*)&seg[wv][6 + c0l] = st;
                if (isH) {
                    const v2f hs = hx + hy;
                    const v2f hd = hx - hy;
                    v4f ht = {hs.x, hd.x, hs.y, hd.y};
                    *(v4f*)&seg[wv][hidx] = ht;
                }
            }

            // ---- issue next row's loads (consumed next iteration) ----
            if (i < ITERS - 1) {
                const int r = r0 - 4 + i;
                px = z2; py = z2; hx = z2; hy = z2;
                if ((unsigned)r < IMG_H) {
                    const float* xr = xb + (size_t)r * IMG_W;
                    const float* yr = yb + (size_t)r * IMG_W;
                    px = *(const v2f*)(xr + cown);
                    py = *(const v2f*)(yr + cown);
                    if (isH && (unsigned)hcol < IMG_W) {
                        hx = *(const v2f*)(xr + hcol);
                        hy = *(const v2f*)(yr + hcol);
                    }
                }
            }

            // ---- horizontal conv from wave-private LDS ----
            // window element j (0..13) at seg idx c0l+j (col cown-6+j);
            // 7 b128 reads, squares once per element.
            v2f hA = z2, hB = z2, qA = z2, qB = z2;
            #pragma unroll
            for (int m = 0; m < 7; ++m) {
                const v4f w4 = *(const v4f*)&seg[wv][c0l + 2 * m];
                const v2f e0 = {w4.x, w4.y};   // j = 2m
                const v2f e1 = {w4.z, w4.w};   // j = 2m+1
                {
                    const int j = 2 * m;
                    if (j >= 1) {
                        const v2f f0 = e0 * e0;          // v_pk_mul_f32
                        if (j <= 11) {
                            hA = pkfma(g[j - 1], e0, hA);
                            qA = pkfma(g[j - 1], f0, qA);
                        }
                        if (j >= 2) {
                            hB = pkfma(g[j - 2], e0, hB);
                            qB = pkfma(g[j - 2], f0, qB);
                        }
                    }
                }
                {
                    const int j = 2 * m + 1;
                    if (j <= 12) {
                        const v2f f1 = e1 * e1;
                        if (j <= 11) {
                            hA = pkfma(g[j - 1], e1, hA);
                            qA = pkfma(g[j - 1], f1, qA);
                        }
                        if (j >= 2) {
                            hB = pkfma(g[j - 2], e1, hB);
                            qB = pkfma(g[j - 2], f1, qB);
                        }
                    }
                }
            }
            rSD[s][0] = hA; rSD[s][1] = hB;
            rQ[s][0]  = qA; rQ[s][1]  = qB;

            // ---- vertical conv + SSIM epilogue (output row r0 + i - 10) ----
            if (i >= 10) {                       // wave-uniform
                const int orow = r0 + i - 10;
                if (orow < IMG_H) {              // wave-uniform tail guard
                    #pragma unroll
                    for (int cc = 0; cc < 2; ++cc) {
                        v2f mSD = z2, mQ = z2;
                        #pragma unroll
                        for (int j = 0; j < 11; ++j) {
                            const int sl = (s + 1 + j) % 11;   // static
                            mSD = pkfma(g[j], rSD[sl][cc], mSD);
                            mQ  = pkfma(g[j], rQ[sl][cc],  mQ);
                        }
                        const v2f t2 = mSD * mSD;      // (mS^2, mD^2)
                        const float a    = 0.5f  * (t2.x + t2.y); // mx2+my2
                        const float muxy = 0.25f * (t2.x - t2.y); // mx*my
                        const float ep   = 0.5f  * (mQ.x + mQ.y); // Ex2+Ey2
                        const float eq   = 0.25f * (mQ.x - mQ.y); // Exy
                        const float sxy  = eq - muxy;
                        const float ssum = ep - a;
                        const float num  = fmaf(2.f, muxy, C1F) * fmaf(2.f, sxy, C2F);
                        const float den  = (a + C1F) * (ssum + C2F);
                        float v = num * __builtin_amdgcn_rcpf(den + EPSF);
                        acc += fminf(fmaxf(v, 0.f), 1.f);
                    }
                }
            }
        }
    }

    // block reduction: wave shuffle, 4 slots in LDS, one atomic per block.
    // (The only __syncthreads in the kernel.)
    #pragma unroll
    for (int off = 32; off > 0; off >>= 1)
        acc += __shfl_down(acc, off, 64);
    if (lane == 0) wredS[wv] = acc;
    __syncthreads();
    if (t == 0) {
        const float tot = (wredS[0] + wredS[1]) + (wredS[2] + wredS[3]);
        atomicAdd(out, tot * (1.0f / (float)((size_t)NIMG * IMG_H * IMG_W)));
    }
}

extern "C" void kernel_launch(void* const* d_in, const int* in_sizes, int n_in,
                              void* d_out, int out_size, void* d_ws, size_t ws_size,
                              hipStream_t stream) {
    const float* x = (const float*)d_in[0];
    const float* y = (const float*)d_in[1];
    const float* w = (const float*)d_in[2];
    float* out = (float*)d_out;

    // d_out is re-poisoned to 0xAA before every timed launch; zero it first.
    hipMemsetAsync(out, 0, sizeof(float), stream);

    dim3 grid((IMG_H + RROWS - 1) / RROWS, NIMG);  // (23, 32) = 736 blocks
    ssim_kernel<<<grid, dim3(NT), 0, stream>>>(x, y, w, out);
}